// Round 7
// baseline (64.334 us; speedup 1.0000x reference)
//
#include <hip/hip_runtime.h>

// Problem constants (match reference)
#define B_ 16
#define N_ 8192
#define U_ 64        // INPUT_DIM
#define W_ 128       // LATENT_DIM
#define BLOCKS_PER_B 32
#define ROWS_PER_BLOCK (N_ / BLOCKS_PER_B)   // 256
#define GRID_ (B_ * BLOCKS_PER_B)            // 512 blocks

#define SENT 0x5AC3F00Du

// Single-kernel design (no memset node, no second dispatch, no grid sync):
//  * every block reduces its 256-row slice to a 256-float partial
//    (slot = u*4 + j; j==0 -> sum feat_u, j=1..3 -> sum feat_u*nhat_{j-1})
//    and stores it to its own ws slice (initialization-free);
//  * __threadfence + release-store of a per-block sentinel flag;
//  * the chunk==0 block of each batch spins on its 31 siblings' flags
//    (producers never spin -> deadlock-free under any scheduling), then
//    combines the 32 partials, applies the [64]->[512] linear map, writes
//    out[b] directly (single writer -> bitwise deterministic), and resets
//    its flags to 0 so the next graph replay starts clean.
// ws layout: [512][256] float partials (512 KiB), then 512 u32 flags.

__global__ __launch_bounds__(256) void so3_onekernel(
    const float* __restrict__ feat,   // [B,N,64]
    const float* __restrict__ pos,    // [B,N,3]
    const float* __restrict__ W0,     // [64,128]
    const float* __restrict__ W1,     // [64,128]
    float* __restrict__ out,          // [B,512]
    float* __restrict__ ws)           // 512 KiB partials + flags
{
    const int blk   = blockIdx.x;              // 0..511
    const int b     = blk >> 5;                // batch
    const int chunk = blk & 31;                // chunk within batch
    const int row0  = chunk * ROWS_PER_BLOCK;
    const int tid   = threadIdx.x;             // 0..255 (4 waves)
    const int grp   = tid & 15;                // feature group: features 4*grp..4*grp+3
    const int rsub  = tid >> 4;                // 0..15: row within a 16-row group

    unsigned* flags = (unsigned*)((char*)ws + (GRID_ * 256 * sizeof(float)));

    float accS[4] = {0.f, 0.f, 0.f, 0.f};
    float accM[4][3] = {{0.f,0.f,0.f},{0.f,0.f,0.f},{0.f,0.f,0.f},{0.f,0.f,0.f}};

    const float4* fbase = (const float4*)(feat + (size_t)b * N_ * U_);
    const float*  pbase = pos + (size_t)b * N_ * 3;

    #pragma unroll
    for (int it = 0; it < ROWS_PER_BLOCK; it += 16) {
        const int n = row0 + it + rsub;
        const float4 f = fbase[(size_t)n * 16 + grp];   // 16 B/lane; wave = 1 KiB contiguous
        const float px = pbase[n * 3 + 0];
        const float py = pbase[n * 3 + 1];
        const float pz = pbase[n * 3 + 2];
        const float inv = rsqrtf(px * px + py * py + pz * pz);
        const float nx = px * inv, ny = py * inv, nz = pz * inv;

        accS[0] += f.x; accS[1] += f.y; accS[2] += f.z; accS[3] += f.w;
        accM[0][0] += f.x * nx; accM[0][1] += f.x * ny; accM[0][2] += f.x * nz;
        accM[1][0] += f.y * nx; accM[1][1] += f.y * ny; accM[1][2] += f.y * nz;
        accM[2][0] += f.z * nx; accM[2][1] += f.z * ny; accM[2][2] += f.z * nz;
        accM[3][0] += f.w * nx; accM[3][1] += f.w * ny; accM[3][2] += f.w * nz;
    }

    // Block-level combine via LDS (pad 17 breaks the stride-16 bank pattern).
    __shared__ float lds[256][17];
    lds[tid][0] = accS[0]; lds[tid][1] = accS[1];
    lds[tid][2] = accS[2]; lds[tid][3] = accS[3];
    #pragma unroll
    for (int i = 0; i < 4; ++i) {
        lds[tid][4 + i * 3 + 0] = accM[i][0];
        lds[tid][4 + i * 3 + 1] = accM[i][1];
        lds[tid][4 + i * 3 + 2] = accM[i][2];
    }
    __syncthreads();

    {
        const int u    = tid >> 2;     // 0..63
        const int j    = tid & 3;      // 0 = S, 1..3 = M[k]
        const int ug   = u >> 2;       // writer feature-group
        const int sub  = u & 3;        // which of writer's 4 features
        const int slot = (j == 0) ? sub : (4 + sub * 3 + (j - 1));
        float s = 0.f;
        #pragma unroll
        for (int src = 0; src < 16; ++src) {
            const int t = (src & 3) * 64 + (src >> 2) * 16 + ug;
            s += lds[t][slot];
        }
        ws[(size_t)blk * 256 + tid] = s;   // coalesced 1 KiB store
    }

    // Publish: make this block's partial device-visible, then release the flag.
    __threadfence();
    __syncthreads();
    if (tid == 0)
        __hip_atomic_store(&flags[blk], SENT, __ATOMIC_RELEASE, __HIP_MEMORY_SCOPE_AGENT);

    if (chunk != 0) return;

    // ---- finalizer for batch b (one block per batch) ----
    if (tid < BLOCKS_PER_B) {
        while (__hip_atomic_load(&flags[(b << 5) + tid], __ATOMIC_RELAXED,
                                 __HIP_MEMORY_SCOPE_AGENT) != SENT)
            __builtin_amdgcn_s_sleep(1);
    }
    __syncthreads();
    __threadfence();   // acquire side: order/refresh before reading partials
    // Reset flags now (no other block reads them this launch); next replay sees 0.
    if (tid < BLOCKS_PER_B)
        __hip_atomic_store(&flags[(b << 5) + tid], 0u, __ATOMIC_RELAXED,
                           __HIP_MEMORY_SCOPE_AGENT);

    // Combine 32 chunk partials, float4-wide: thread (cgrp, u4) sums 8 chunks.
    const int u4   = tid & 63;      // float4 index within a 256-float row
    const int cgrp = tid >> 6;      // 0..3

    __shared__ float4 smf4[4][64];
    __shared__ float  sm[256];
    {
        const float4* base = (const float4*)(ws + (size_t)(b << 5) * 256);
        float4 a = {0.f, 0.f, 0.f, 0.f};
        #pragma unroll
        for (int c = 0; c < 8; ++c) {
            const float4 v = base[(size_t)(cgrp * 8 + c) * 64 + u4];
            a.x += v.x; a.y += v.y; a.z += v.z; a.w += v.w;
        }
        smf4[cgrp][u4] = a;
    }
    __syncthreads();
    if (tid < 64) {
        float4 t = smf4[0][tid];
        #pragma unroll
        for (int g = 1; g < 4; ++g) {
            const float4 v = smf4[g][tid];
            t.x += v.x; t.y += v.y; t.z += v.z; t.w += v.w;
        }
        ((float4*)sm)[tid] = t;     // sm[u*4 + j]
    }
    __syncthreads();

    // Tiny matmul: 512 outputs over 256 threads = 2 each; direct stores.
    const float scaleS = 0.125f / (float)N_;                       // PATH_COEFF / N
    const float scaleV = 0.125f * 1.7320508075688772f / (float)N_; // PATH_COEFF*sqrt(3)/N

    #pragma unroll
    for (int half = 0; half < 2; ++half) {
        const int o = tid + half * 256;
        float acc = 0.f;
        if (o < 128) {
            #pragma unroll
            for (int u = 0; u < 64; ++u) acc += sm[u * 4] * W0[u * 128 + o];
            out[b * 512 + o] = acc * scaleS;
        } else {
            const int idx = o - 128;       // 0..383
            const int w = idx / 3;
            const int k = idx - 3 * w;
            #pragma unroll
            for (int u = 0; u < 64; ++u) acc += sm[u * 4 + 1 + k] * W1[u * 128 + w];
            out[b * 512 + 128 + idx] = acc * scaleV;
        }
    }
}

extern "C" void kernel_launch(void* const* d_in, const int* in_sizes, int n_in,
                              void* d_out, int out_size, void* d_ws, size_t ws_size,
                              hipStream_t stream) {
    const float* feat = (const float*)d_in[0];
    const float* pos  = (const float*)d_in[1];
    const float* W0   = (const float*)d_in[2];
    const float* W1   = (const float*)d_in[3];
    float* out = (float*)d_out;
    float* ws  = (float*)d_ws;   // needs 512*256*4 + 512*4 = 526 KiB (<= 1 MiB proven in R2)

    so3_onekernel<<<GRID_, 256, 0, stream>>>(feat, pos, W0, W1, out, ws);
}

// Round 8
// 30.286 us; speedup vs baseline: 2.1242x; 2.1242x over previous
//
#include <hip/hip_runtime.h>

// Problem constants (match reference)
#define B_ 16
#define N_ 8192
#define U_ 64        // INPUT_DIM
#define W_ 128       // LATENT_DIM
#define BLOCKS_PER_B 64
#define ROWS_PER_BLOCK (N_ / BLOCKS_PER_B)   // 128
#define GRID_ (B_ * BLOCKS_PER_B)            // 1024 blocks, 4/CU

// ws layout: [B_*256] float stats (16 KB), then B_ u32 ticket counters.
// stats slot = u*4 + j; j==0 -> sum feat_u, j=1..3 -> sum feat_u * nhat_{j-1}.
// Both zeroed by one 16.4 KB memset node each launch.
//
// Design (fence-free single compute kernel):
//  * block reduces its 128-row slice in LDS -> 256 stats, atomicAdd into
//    stats[b] (agent-scope RMWs execute at the device coherence point; no
//    __threadfence -- R7 proved fences cost ~50+ us on gfx950).
//  * s_waitcnt vmcnt(0) (completion wait, not a cache op) + __syncthreads,
//    then tid0 takes a relaxed ticket. old==63 -> this is the last block of
//    batch b: all 64 blocks' RMWs have completed at the coherence point.
//  * winner re-reads stats with relaxed ATOMIC loads (bypass L1/L2, served
//    from the coherence point), applies the [64]->[512] map, writes out[b]
//    directly (sole writer).
// out layout: [B,512]: o<128 scalar path, 128+3w+k vector path.

__global__ __launch_bounds__(256) void so3_mega_kernel(
    const float* __restrict__ feat,   // [B,N,64]
    const float* __restrict__ pos,    // [B,N,3]
    const float* __restrict__ W0,     // [64,128]
    const float* __restrict__ W1,     // [64,128]
    float* __restrict__ out,          // [B,512]
    float* __restrict__ ws)           // stats + tickets (pre-zeroed this launch)
{
    const int blk   = blockIdx.x;              // 0..1023
    const int b     = blk / BLOCKS_PER_B;
    const int chunk = blk % BLOCKS_PER_B;
    const int row0  = chunk * ROWS_PER_BLOCK;
    const int tid   = threadIdx.x;             // 0..255 (4 waves)
    const int grp   = tid & 15;                // feature group: features 4*grp..4*grp+3
    const int rsub  = tid >> 4;                // 0..15: row within a 16-row group

    float*    stats   = ws;                                   // [B_*256]
    unsigned* tickets = (unsigned*)(ws + B_ * 256);           // [B_]

    float accS[4] = {0.f, 0.f, 0.f, 0.f};
    float accM[4][3] = {{0.f,0.f,0.f},{0.f,0.f,0.f},{0.f,0.f,0.f},{0.f,0.f,0.f}};

    const float4* fbase = (const float4*)(feat + (size_t)b * N_ * U_);
    const float*  pbase = pos + (size_t)b * N_ * 3;

    #pragma unroll
    for (int it = 0; it < ROWS_PER_BLOCK; it += 16) {
        const int n = row0 + it + rsub;
        const float4 f = fbase[(size_t)n * 16 + grp];   // 16 B/lane; wave = 1 KiB contiguous
        const float px = pbase[n * 3 + 0];
        const float py = pbase[n * 3 + 1];
        const float pz = pbase[n * 3 + 2];
        const float inv = rsqrtf(px * px + py * py + pz * pz);
        const float nx = px * inv, ny = py * inv, nz = pz * inv;

        accS[0] += f.x; accS[1] += f.y; accS[2] += f.z; accS[3] += f.w;
        accM[0][0] += f.x * nx; accM[0][1] += f.x * ny; accM[0][2] += f.x * nz;
        accM[1][0] += f.y * nx; accM[1][1] += f.y * ny; accM[1][2] += f.y * nz;
        accM[2][0] += f.z * nx; accM[2][1] += f.z * ny; accM[2][2] += f.z * nz;
        accM[3][0] += f.w * nx; accM[3][1] += f.w * ny; accM[3][2] += f.w * nz;
    }

    // Block-level combine via LDS (pad 17 breaks the stride-16 bank pattern).
    __shared__ float lds[256][17];
    lds[tid][0] = accS[0]; lds[tid][1] = accS[1];
    lds[tid][2] = accS[2]; lds[tid][3] = accS[3];
    #pragma unroll
    for (int i = 0; i < 4; ++i) {
        lds[tid][4 + i * 3 + 0] = accM[i][0];
        lds[tid][4 + i * 3 + 1] = accM[i][1];
        lds[tid][4 + i * 3 + 2] = accM[i][2];
    }
    __syncthreads();

    {
        const int u    = tid >> 2;     // 0..63
        const int j    = tid & 3;      // 0 = S, 1..3 = M[k]
        const int ug   = u >> 2;       // writer feature-group
        const int sub  = u & 3;        // which of writer's 4 features
        const int slot = (j == 0) ? sub : (4 + sub * 3 + (j - 1));
        float s = 0.f;
        #pragma unroll
        for (int src = 0; src < 16; ++src) {
            const int t = (src & 3) * 64 + (src >> 2) * 16 + ug;
            s += lds[t][slot];
        }
        // stat index == tid (u*4+j == (tid&~3)+(tid&3)); 64 lanes -> 64
        // consecutive addresses. Relaxed agent-scope RMW, no fence.
        atomicAdd(&stats[b * 256 + tid], s);
    }

    // Wait for THIS wave's RMWs to complete at the coherence point (pure
    // counter wait -- no cache writeback/invalidate), then block-wide barrier
    // so all 4 waves' adds are complete before taking the ticket.
    asm volatile("s_waitcnt vmcnt(0)" ::: "memory");
    __syncthreads();

    __shared__ unsigned s_win;
    if (tid == 0) {
        const unsigned old = __hip_atomic_fetch_add(&tickets[b], 1u,
                                                    __ATOMIC_RELAXED,
                                                    __HIP_MEMORY_SCOPE_AGENT);
        s_win = (old == BLOCKS_PER_B - 1) ? 1u : 0u;
    }
    __syncthreads();
    if (!s_win) return;

    // ---- winner: finalize batch b ----
    if (tid == 0)   // belt-and-suspenders acquire (single cheap inv)
        (void)__hip_atomic_load(&tickets[b], __ATOMIC_ACQUIRE,
                                __HIP_MEMORY_SCOPE_AGENT);
    __syncthreads();

    __shared__ float sm[256];
    // Relaxed atomic loads: served from the coherence point where the RMWs
    // executed; no stale L1/L2 copies possible.
    sm[tid] = __hip_atomic_load(&stats[b * 256 + tid], __ATOMIC_RELAXED,
                                __HIP_MEMORY_SCOPE_AGENT);
    __syncthreads();

    const float scaleS = 0.125f / (float)N_;                       // PATH_COEFF / N
    const float scaleV = 0.125f * 1.7320508075688772f / (float)N_; // PATH_COEFF*sqrt(3)/N

    #pragma unroll
    for (int half = 0; half < 2; ++half) {
        const int o = tid + half * 256;
        float acc = 0.f;
        if (o < 128) {
            #pragma unroll
            for (int u = 0; u < 64; ++u) acc += sm[u * 4] * W0[u * 128 + o];
            out[b * 512 + o] = acc * scaleS;
        } else {
            const int idx = o - 128;       // 0..383
            const int w = idx / 3;
            const int k = idx - 3 * w;
            #pragma unroll
            for (int u = 0; u < 64; ++u) acc += sm[u * 4 + 1 + k] * W1[u * 128 + w];
            out[b * 512 + 128 + idx] = acc * scaleV;
        }
    }
}

extern "C" void kernel_launch(void* const* d_in, const int* in_sizes, int n_in,
                              void* d_out, int out_size, void* d_ws, size_t ws_size,
                              hipStream_t stream) {
    const float* feat = (const float*)d_in[0];
    const float* pos  = (const float*)d_in[1];
    const float* W0   = (const float*)d_in[2];
    const float* W1   = (const float*)d_in[3];
    float* out = (float*)d_out;
    float* ws  = (float*)d_ws;

    // Zero stats (16 KB) + tickets (64 B) each launch; atomic targets.
    hipMemsetAsync(ws, 0, (size_t)(B_ * 256) * sizeof(float) + B_ * sizeof(unsigned),
                   stream);

    so3_mega_kernel<<<GRID_, 256, 0, stream>>>(feat, pos, W0, W1, out, ws);
}

// Round 10
// 14.045 us; speedup vs baseline: 4.5804x; 2.1563x over previous
//
#include <hip/hip_runtime.h>

// Problem constants (match reference)
#define B_ 16
#define N_ 8192
#define U_ 64        // INPUT_DIM
#define W_ 128       // LATENT_DIM
#define BLOCKS_PER_B 32
#define ROWS_PER_BLOCK (N_ / BLOCKS_PER_B)   // 256
#define GRID_ (B_ * BLOCKS_PER_B)            // 512 blocks = 2 clean rounds over 256 CUs

// Clang ext-vector float4: accepted by __builtin_nontemporal_load (HIP's
// float4 class is not).
typedef float f32x4 __attribute__((ext_vector_type(4)));

// ws layout: [GRID_][256] block-partial sums (512 KiB).
//   slot = u*4 + j; j==0 -> sum feat_u, j=1..3 -> sum feat_u * nhat_{j-1}
// out layout: [B,512]: o<128 scalar path, 128+3w+k vector path
//
// Structure note (R4/R7/R8 post-mortems): grid-sync, threadfence-publish and
// atomic-completion-wait all cost 15-110 us on gfx950 (non-coherent per-XCD
// L2s). The dependency-free two-kernel pipeline is the proven structure; this
// round only improves BW efficiency (nontemporal streaming loads) and halves
// the partial traffic (32 chunks/batch instead of 64).

__global__ __launch_bounds__(256) void so3_reduce_kernel(
    const float* __restrict__ feat,   // [B,N,64]
    const float* __restrict__ pos,    // [B,N,3]
    float* __restrict__ ws)           // [GRID_][256] partials (written, not accumulated)
{
    const int blk   = blockIdx.x;              // 0..GRID_-1
    const int b     = blk / BLOCKS_PER_B;
    const int chunk = blk % BLOCKS_PER_B;
    const int row0  = chunk * ROWS_PER_BLOCK;
    const int tid   = threadIdx.x;             // 0..255 (4 waves)
    const int grp   = tid & 15;                // feature group: features 4*grp .. 4*grp+3
    const int rsub  = tid >> 4;                // 0..15: row within a 16-row group

    float accS[4] = {0.f, 0.f, 0.f, 0.f};
    float accM[4][3] = {{0.f,0.f,0.f},{0.f,0.f,0.f},{0.f,0.f,0.f},{0.f,0.f,0.f}};

    const f32x4* fbase = (const f32x4*)(feat + (size_t)b * N_ * U_);
    const float* pbase = pos + (size_t)b * N_ * 3;

    #pragma unroll
    for (int it = 0; it < ROWS_PER_BLOCK; it += 16) {
        const int n = row0 + it + rsub;
        // 16 B/lane; wave = 1 KiB contiguous. Streaming data read exactly
        // once -> nontemporal (no L2 allocation).
        const f32x4 f = __builtin_nontemporal_load(&fbase[(size_t)n * 16 + grp]);
        const float px = __builtin_nontemporal_load(&pbase[n * 3 + 0]);
        const float py = __builtin_nontemporal_load(&pbase[n * 3 + 1]);
        const float pz = __builtin_nontemporal_load(&pbase[n * 3 + 2]);
        const float inv = rsqrtf(px * px + py * py + pz * pz);
        const float nx = px * inv, ny = py * inv, nz = pz * inv;

        accS[0] += f.x; accS[1] += f.y; accS[2] += f.z; accS[3] += f.w;
        accM[0][0] += f.x * nx; accM[0][1] += f.x * ny; accM[0][2] += f.x * nz;
        accM[1][0] += f.y * nx; accM[1][1] += f.y * ny; accM[1][2] += f.y * nz;
        accM[2][0] += f.z * nx; accM[2][1] += f.z * ny; accM[2][2] += f.z * nz;
        accM[3][0] += f.w * nx; accM[3][1] += f.w * ny; accM[3][2] += f.w * nz;
    }

    // Block-level combine via LDS (pad 17 breaks the stride-16 bank pattern).
    __shared__ float lds[256][17];
    lds[tid][0] = accS[0]; lds[tid][1] = accS[1];
    lds[tid][2] = accS[2]; lds[tid][3] = accS[3];
    #pragma unroll
    for (int i = 0; i < 4; ++i) {
        lds[tid][4 + i * 3 + 0] = accM[i][0];
        lds[tid][4 + i * 3 + 1] = accM[i][1];
        lds[tid][4 + i * 3 + 2] = accM[i][2];
    }
    __syncthreads();

    const int u    = tid >> 2;     // 0..63
    const int j    = tid & 3;      // 0 = S, 1..3 = M[k]
    const int ug   = u >> 2;       // writer feature-group
    const int sub  = u & 3;        // which of writer's 4 features
    const int slot = (j == 0) ? sub : (4 + sub * 3 + (j - 1));
    float s = 0.f;
    #pragma unroll
    for (int src = 0; src < 16; ++src) {
        const int t = (src & 3) * 64 + (src >> 2) * 16 + ug;  // wave*64 + row-in-wave*16 + ug
        s += lds[t][slot];
    }
    ws[(size_t)blk * 256 + tid] = s;   // coalesced 1 KiB store
}

__global__ __launch_bounds__(512) void so3_finalize_kernel(
    const float* __restrict__ ws,   // [GRID_][256] partials
    const float* __restrict__ W0,   // [64,128]
    const float* __restrict__ W1,   // [64,128]
    float* __restrict__ out)        // [B,512]
{
    const int b   = blockIdx.x;
    const int tid = threadIdx.x;    // 0..511

    // Phase 1: cross-block combine, float4-wide. Slot group of 4 = one u
    // (slot = u*4 + j): thread (cgrp, u4) sums float4 over 4 chunks.
    const int u4   = tid & 63;      // float4 index within a chunk row
    const int cgrp = tid >> 6;      // 0..7: chunk group

    __shared__ float4 smf4[8][64];  // 8 KiB
    __shared__ float  sm[256];

    {
        const float4* base = (const float4*)(ws + (size_t)b * BLOCKS_PER_B * 256);
        float4 a = {0.f, 0.f, 0.f, 0.f};
        #pragma unroll
        for (int c = 0; c < 4; ++c) {
            const float4 v = base[(size_t)(cgrp * 4 + c) * 64 + u4];
            a.x += v.x; a.y += v.y; a.z += v.z; a.w += v.w;
        }
        smf4[cgrp][u4] = a;
    }
    __syncthreads();

    if (tid < 64) {
        float4 t = smf4[0][tid];
        #pragma unroll
        for (int g = 1; g < 8; ++g) {
            const float4 v = smf4[g][tid];
            t.x += v.x; t.y += v.y; t.z += v.z; t.w += v.w;
        }
        ((float4*)sm)[tid] = t;     // sm[u*4 + j]
    }
    __syncthreads();

    // Phase 2: tiny matmul, one output element per thread.
    const float scaleS = 0.125f / (float)N_;                       // PATH_COEFF / N
    const float scaleV = 0.125f * 1.7320508075688772f / (float)N_; // PATH_COEFF*sqrt(3)/N

    const int o = tid;
    float acc = 0.f;
    if (o < 128) {
        #pragma unroll
        for (int uu = 0; uu < 64; ++uu) acc += sm[uu * 4] * W0[uu * 128 + o];
        out[b * 512 + o] = acc * scaleS;
    } else {
        const int idx = o - 128;       // 0..383
        const int w = idx / 3;
        const int k = idx - 3 * w;
        #pragma unroll
        for (int uu = 0; uu < 64; ++uu) acc += sm[uu * 4 + 1 + k] * W1[uu * 128 + w];
        out[b * 512 + 128 + idx] = acc * scaleV;
    }
}

extern "C" void kernel_launch(void* const* d_in, const int* in_sizes, int n_in,
                              void* d_out, int out_size, void* d_ws, size_t ws_size,
                              hipStream_t stream) {
    const float* feat = (const float*)d_in[0];
    const float* pos  = (const float*)d_in[1];
    const float* W0   = (const float*)d_in[2];
    const float* W1   = (const float*)d_in[3];
    float* out = (float*)d_out;
    float* ws  = (float*)d_ws;   // needs GRID_*256*4 = 512 KiB scratch

    so3_reduce_kernel<<<GRID_, 256, 0, stream>>>(feat, pos, ws);
    so3_finalize_kernel<<<B_, 512, 0, stream>>>(ws, W0, W1, out);
}

// Round 11
// 12.962 us; speedup vs baseline: 4.9633x; 1.0836x over previous
//
#include <hip/hip_runtime.h>

// Problem constants (match reference)
#define B_ 16
#define N_ 8192
#define U_ 64        // INPUT_DIM
#define W_ 128       // LATENT_DIM
#define BLOCKS_PER_B 32
#define ROWS_PER_BLOCK (N_ / BLOCKS_PER_B)   // 256 = blockDim
#define GRID_ (B_ * BLOCKS_PER_B)            // 512 blocks = 2 rounds over 256 CUs

// Clang ext-vector float4: accepted by __builtin_nontemporal_load and usable
// in LDS for single-instruction ds_read_b128.
typedef float f32x4 __attribute__((ext_vector_type(4)));

// ws layout: [GRID_][256] block-partial sums (512 KiB).
//   slot = u*4 + j; j==0 -> sum feat_u, j=1..3 -> sum feat_u * nhat_{j-1}
// out layout: [B,512]: o<128 scalar path, 128+3w+k vector path
//
// Structure note (R4/R7/R8): grid-sync / threadfence / atomic-wait cost
// 15-110 us on gfx950 (non-coherent per-XCD L2s) -> dependency-free 2-kernel
// pipeline. This round: reduce VMEM issue pressure in the reduce loop
// (1 VMEM instr/iter instead of 4; rsqrt once per row instead of 16x)
// -- the input is largely L3-resident so the loop is issue-, not HBM-bound.

__global__ __launch_bounds__(256) void so3_reduce_kernel(
    const float* __restrict__ feat,   // [B,N,64]
    const float* __restrict__ pos,    // [B,N,3]
    float* __restrict__ ws)           // [GRID_][256] partials
{
    const int blk   = blockIdx.x;              // 0..GRID_-1
    const int b     = blk / BLOCKS_PER_B;
    const int chunk = blk % BLOCKS_PER_B;
    const int row0  = chunk * ROWS_PER_BLOCK;
    const int tid   = threadIdx.x;             // 0..255 (4 waves)
    const int grp   = tid & 15;                // feature group: feats 4*grp..4*grp+3
    const int rsub  = tid >> 4;                // 0..15: row within a 16-row group

    // ---- prologue: normalize pos once per row into LDS ----
    __shared__ f32x4 nlds[ROWS_PER_BLOCK];     // 4 KiB, 16B-aligned entries
    {
        const float* p = pos + ((size_t)b * N_ + row0 + tid) * 3;
        const float px = p[0], py = p[1], pz = p[2];   // block-coalesced 3 KiB
        const float inv = rsqrtf(px * px + py * py + pz * pz);
        f32x4 v;
        v.x = px * inv; v.y = py * inv; v.z = pz * inv; v.w = 0.f;
        nlds[tid] = v;
    }
    __syncthreads();

    float accS[4] = {0.f, 0.f, 0.f, 0.f};
    float accM[4][3] = {{0.f,0.f,0.f},{0.f,0.f,0.f},{0.f,0.f,0.f},{0.f,0.f,0.f}};

    const f32x4* fbase = (const f32x4*)(feat + (size_t)b * N_ * U_);

    #pragma unroll
    for (int it = 0; it < ROWS_PER_BLOCK; it += 16) {
        const int nl = it + rsub;              // local row 0..255
        // 16 B/lane; wave = 1 KiB contiguous; read-once -> nontemporal.
        const f32x4 f = __builtin_nontemporal_load(
            &fbase[(size_t)(row0 + nl) * 16 + grp]);
        const f32x4 nv = nlds[nl];             // ds_read_b128, 16-way broadcast
        const float nx = nv.x, ny = nv.y, nz = nv.z;

        accS[0] += f.x; accS[1] += f.y; accS[2] += f.z; accS[3] += f.w;
        accM[0][0] += f.x * nx; accM[0][1] += f.x * ny; accM[0][2] += f.x * nz;
        accM[1][0] += f.y * nx; accM[1][1] += f.y * ny; accM[1][2] += f.y * nz;
        accM[2][0] += f.z * nx; accM[2][1] += f.z * ny; accM[2][2] += f.z * nz;
        accM[3][0] += f.w * nx; accM[3][1] += f.w * ny; accM[3][2] += f.w * nz;
    }

    // Block-level combine via LDS (pad 17 breaks the stride-16 bank pattern).
    __shared__ float lds[256][17];
    lds[tid][0] = accS[0]; lds[tid][1] = accS[1];
    lds[tid][2] = accS[2]; lds[tid][3] = accS[3];
    #pragma unroll
    for (int i = 0; i < 4; ++i) {
        lds[tid][4 + i * 3 + 0] = accM[i][0];
        lds[tid][4 + i * 3 + 1] = accM[i][1];
        lds[tid][4 + i * 3 + 2] = accM[i][2];
    }
    __syncthreads();

    const int u    = tid >> 2;     // 0..63
    const int j    = tid & 3;      // 0 = S, 1..3 = M[k]
    const int ug   = u >> 2;       // writer feature-group
    const int sub  = u & 3;        // which of writer's 4 features
    const int slot = (j == 0) ? sub : (4 + sub * 3 + (j - 1));
    float s = 0.f;
    #pragma unroll
    for (int src = 0; src < 16; ++src) {
        const int t = (src & 3) * 64 + (src >> 2) * 16 + ug;  // wave*64 + row-in-wave*16 + ug
        s += lds[t][slot];
    }
    ws[(size_t)blk * 256 + tid] = s;   // coalesced 1 KiB store
}

__global__ __launch_bounds__(512) void so3_finalize_kernel(
    const float* __restrict__ ws,   // [GRID_][256] partials
    const float* __restrict__ W0,   // [64,128]
    const float* __restrict__ W1,   // [64,128]
    float* __restrict__ out)        // [B,512]
{
    const int b   = blockIdx.x;
    const int tid = threadIdx.x;    // 0..511

    // Phase 1: cross-block combine, float4-wide (slot group of 4 = one u).
    const int u4   = tid & 63;      // float4 index within a chunk row
    const int cgrp = tid >> 6;      // 0..7: chunk group

    __shared__ float4 smf4[8][64];  // 8 KiB
    __shared__ float  sm[256];

    {
        const float4* base = (const float4*)(ws + (size_t)b * BLOCKS_PER_B * 256);
        float4 a = {0.f, 0.f, 0.f, 0.f};
        #pragma unroll
        for (int c = 0; c < 4; ++c) {
            const float4 v = base[(size_t)(cgrp * 4 + c) * 64 + u4];
            a.x += v.x; a.y += v.y; a.z += v.z; a.w += v.w;
        }
        smf4[cgrp][u4] = a;
    }
    __syncthreads();

    if (tid < 64) {
        float4 t = smf4[0][tid];
        #pragma unroll
        for (int g = 1; g < 8; ++g) {
            const float4 v = smf4[g][tid];
            t.x += v.x; t.y += v.y; t.z += v.z; t.w += v.w;
        }
        ((float4*)sm)[tid] = t;     // sm[u*4 + j]
    }
    __syncthreads();

    // Phase 2: tiny matmul, one output element per thread.
    const float scaleS = 0.125f / (float)N_;                       // PATH_COEFF / N
    const float scaleV = 0.125f * 1.7320508075688772f / (float)N_; // PATH_COEFF*sqrt(3)/N

    const int o = tid;
    float acc = 0.f;
    if (o < 128) {
        #pragma unroll
        for (int uu = 0; uu < 64; ++uu) acc += sm[uu * 4] * W0[uu * 128 + o];
        out[b * 512 + o] = acc * scaleS;
    } else {
        const int idx = o - 128;       // 0..383
        const int w = idx / 3;
        const int k = idx - 3 * w;
        #pragma unroll
        for (int uu = 0; uu < 64; ++uu) acc += sm[uu * 4 + 1 + k] * W1[uu * 128 + w];
        out[b * 512 + 128 + idx] = acc * scaleV;
    }
}

extern "C" void kernel_launch(void* const* d_in, const int* in_sizes, int n_in,
                              void* d_out, int out_size, void* d_ws, size_t ws_size,
                              hipStream_t stream) {
    const float* feat = (const float*)d_in[0];
    const float* pos  = (const float*)d_in[1];
    const float* W0   = (const float*)d_in[2];
    const float* W1   = (const float*)d_in[3];
    float* out = (float*)d_out;
    float* ws  = (float*)d_ws;   // needs GRID_*256*4 = 512 KiB scratch

    so3_reduce_kernel<<<GRID_, 256, 0, stream>>>(feat, pos, ws);
    so3_finalize_kernel<<<B_, 512, 0, stream>>>(ws, W0, W1, out);
}

// Round 12
// 12.902 us; speedup vs baseline: 4.9862x; 1.0046x over previous
//
#include <hip/hip_runtime.h>

// Problem constants (match reference)
#define B_ 16
#define N_ 8192
#define U_ 64        // INPUT_DIM
#define W_ 128       // LATENT_DIM
#define BLOCKS_PER_B 32
#define ROWS_PER_BLOCK (N_ / BLOCKS_PER_B)   // 256 = blockDim
#define GRID_ (B_ * BLOCKS_PER_B)            // 512 blocks = 2 blocks/CU exactly

typedef float f32x4 __attribute__((ext_vector_type(4)));

// ws layout: [GRID_][256] block-partial sums (512 KiB).
//   slot = u*4 + j; j==0 -> sum feat_u, j=1..3 -> sum feat_u * nhat_{j-1}
// out layout: [B,512]: o<128 scalar path, 128+3w+k vector path
//
// R11 post-mortem: reduce is partly VMEM-latency bound. Grid is 2 blocks/CU
// (grid-limited), so VGPRs are free: __launch_bounds__(256,2) + full 16-deep
// load prefetch (statically indexed -> registers, rule #20) maximizes
// memory-level parallelism. nv.w=1.0 regularizes the accumulator to 16 FMA
// per row (f*1.0+acc is bit-identical to f+acc).

__global__ __launch_bounds__(256, 2) void so3_reduce_kernel(
    const float* __restrict__ feat,   // [B,N,64]
    const float* __restrict__ pos,    // [B,N,3]
    float* __restrict__ ws)           // [GRID_][256] partials
{
    const int blk   = blockIdx.x;              // 0..GRID_-1
    const int b     = blk / BLOCKS_PER_B;
    const int chunk = blk % BLOCKS_PER_B;
    const int row0  = chunk * ROWS_PER_BLOCK;
    const int tid   = threadIdx.x;             // 0..255 (4 waves)
    const int grp   = tid & 15;                // feature group: feats 4*grp..4*grp+3
    const int rsub  = tid >> 4;                // 0..15: row within a 16-row group

    // ---- prologue: normalize pos once per row into LDS ----
    __shared__ f32x4 nlds[ROWS_PER_BLOCK];     // 4 KiB
    {
        const float* p = pos + ((size_t)b * N_ + row0 + tid) * 3;
        const float px = p[0], py = p[1], pz = p[2];   // block-coalesced 3 KiB
        const float inv = rsqrtf(px * px + py * py + pz * pz);
        f32x4 v;
        v.x = px * inv; v.y = py * inv; v.z = pz * inv; v.w = 1.0f;
        nlds[tid] = v;
    }
    __syncthreads();

    const f32x4* fbase = (const f32x4*)(feat + (size_t)b * N_ * U_);

    // ---- full prefetch: issue all 16 nontemporal dwordx4 loads up front ----
    f32x4 fb[16];
    #pragma unroll
    for (int it = 0; it < 16; ++it) {
        const int nl = it * 16 + rsub;         // local row
        fb[it] = __builtin_nontemporal_load(
            &fbase[(size_t)(row0 + nl) * 16 + grp]);
    }

    // acc[i][k]: i = feat sub-index (4*grp+i), k = 0..2 -> M[k], k = 3 -> S.
    float acc[4][4] = {{0.f,0.f,0.f,0.f},{0.f,0.f,0.f,0.f},
                       {0.f,0.f,0.f,0.f},{0.f,0.f,0.f,0.f}};

    #pragma unroll
    for (int it = 0; it < 16; ++it) {
        const int nl = it * 16 + rsub;
        const f32x4 f  = fb[it];
        const f32x4 nv = nlds[nl];             // ds_read_b128, 16-way broadcast
        #pragma unroll
        for (int k = 0; k < 4; ++k) {
            const float nk = (k == 0) ? nv.x : (k == 1) ? nv.y
                           : (k == 2) ? nv.z : nv.w;   // nv.w == 1.0 -> sum
            acc[0][k] = fmaf(f.x, nk, acc[0][k]);
            acc[1][k] = fmaf(f.y, nk, acc[1][k]);
            acc[2][k] = fmaf(f.z, nk, acc[2][k]);
            acc[3][k] = fmaf(f.w, nk, acc[3][k]);
        }
    }

    // Block-level combine via LDS (pad 17 breaks the stride-16 bank pattern).
    // lds[tid][i*4+k] = acc[i][k].
    __shared__ float lds[256][17];
    #pragma unroll
    for (int i = 0; i < 4; ++i) {
        lds[tid][i * 4 + 0] = acc[i][0];
        lds[tid][i * 4 + 1] = acc[i][1];
        lds[tid][i * 4 + 2] = acc[i][2];
        lds[tid][i * 4 + 3] = acc[i][3];
    }
    __syncthreads();

    // ws slot contract (unchanged): slot tid = (u = tid>>2, j = tid&3);
    // j==0 -> S (lds k=3), j=1..3 -> M[j-1] (lds k=j-1).
    const int u    = tid >> 2;     // 0..63
    const int j    = tid & 3;
    const int ug   = u >> 2;       // writer feature-group (grp)
    const int sub  = u & 3;        // writer's sub-index i
    const int slot = (j == 0) ? (sub * 4 + 3) : (sub * 4 + (j - 1));
    float s = 0.f;
    #pragma unroll
    for (int src = 0; src < 16; ++src) {
        const int t = (src & 3) * 64 + (src >> 2) * 16 + ug;  // wave*64 + row-in-wave*16 + ug
        s += lds[t][slot];
    }
    ws[(size_t)blk * 256 + tid] = s;   // coalesced 1 KiB store
}

__global__ __launch_bounds__(512) void so3_finalize_kernel(
    const float* __restrict__ ws,   // [GRID_][256] partials
    const float* __restrict__ W0,   // [64,128]
    const float* __restrict__ W1,   // [64,128]
    float* __restrict__ out)        // [B,512]
{
    const int b   = blockIdx.x;
    const int tid = threadIdx.x;    // 0..511

    // Phase 1: cross-block combine, float4-wide (slot group of 4 = one u).
    const int u4   = tid & 63;      // float4 index within a chunk row
    const int cgrp = tid >> 6;      // 0..7: chunk group

    __shared__ float4 smf4[8][64];  // 8 KiB
    __shared__ float  sm[256];

    {
        const float4* base = (const float4*)(ws + (size_t)b * BLOCKS_PER_B * 256);
        float4 a = {0.f, 0.f, 0.f, 0.f};
        #pragma unroll
        for (int c = 0; c < 4; ++c) {
            const float4 v = base[(size_t)(cgrp * 4 + c) * 64 + u4];
            a.x += v.x; a.y += v.y; a.z += v.z; a.w += v.w;
        }
        smf4[cgrp][u4] = a;
    }
    __syncthreads();

    if (tid < 64) {
        float4 t = smf4[0][tid];
        #pragma unroll
        for (int g = 1; g < 8; ++g) {
            const float4 v = smf4[g][tid];
            t.x += v.x; t.y += v.y; t.z += v.z; t.w += v.w;
        }
        ((float4*)sm)[tid] = t;     // sm[u*4 + j]
    }
    __syncthreads();

    // Phase 2: tiny matmul, one output element per thread.
    const float scaleS = 0.125f / (float)N_;                       // PATH_COEFF / N
    const float scaleV = 0.125f * 1.7320508075688772f / (float)N_; // PATH_COEFF*sqrt(3)/N

    const int o = tid;
    float acc = 0.f;
    if (o < 128) {
        #pragma unroll
        for (int uu = 0; uu < 64; ++uu) acc += sm[uu * 4] * W0[uu * 128 + o];
        out[b * 512 + o] = acc * scaleS;
    } else {
        const int idx = o - 128;       // 0..383
        const int w = idx / 3;
        const int k = idx - 3 * w;
        #pragma unroll
        for (int uu = 0; uu < 64; ++uu) acc += sm[uu * 4 + 1 + k] * W1[uu * 128 + w];
        out[b * 512 + 128 + idx] = acc * scaleV;
    }
}

extern "C" void kernel_launch(void* const* d_in, const int* in_sizes, int n_in,
                              void* d_out, int out_size, void* d_ws, size_t ws_size,
                              hipStream_t stream) {
    const float* feat = (const float*)d_in[0];
    const float* pos  = (const float*)d_in[1];
    const float* W0   = (const float*)d_in[2];
    const float* W1   = (const float*)d_in[3];
    float* out = (float*)d_out;
    float* ws  = (float*)d_ws;   // needs GRID_*256*4 = 512 KiB scratch

    so3_reduce_kernel<<<GRID_, 256, 0, stream>>>(feat, pos, ws);
    so3_finalize_kernel<<<B_, 512, 0, stream>>>(ws, W0, W1, out);
}